// Round 21
// baseline (104.092 us; speedup 1.0000x reference)
//
#include <hip/hip_runtime.h>
#include <hip/hip_fp16.h>
#include <math.h>

#define NN 100000
#define NE 1600000
#define D 64
#define NEG_SLOPE 0.2f
#define NBKT 391          // ceil(NN/256) buckets of 256 dst nodes
#define NBIN 782          // bin blocks (2x machine fill vs 391)
#define CHUNKB 2048       // edges per bin block (782*2048 >= NE, %4==0)
#define BSLOT 5120        // slots per bucket (mean 4096, sd 64)
#define NTILE 1563        // ceil(NN/64) GEMM tiles

typedef __attribute__((ext_vector_type(8))) short short8;
typedef __attribute__((ext_vector_type(4))) float f32x4;

// ---------------- DPP wave reductions (VALU pipe, no LDS) ----------------
template<int CTRL>
__device__ __forceinline__ float dpp_add(float x) {
    int y = __builtin_amdgcn_update_dpp(0, __float_as_int(x), CTRL, 0xf, 0xf, true);
    return x + __int_as_float(y);
}
template<int CTRL>
__device__ __forceinline__ float dpp_max(float x) {
    int xi = __float_as_int(x);
    int y = __builtin_amdgcn_update_dpp(xi, xi, CTRL, 0xf, 0xf, false);
    return fmaxf(x, __int_as_float(y));
}
__device__ __forceinline__ float wave_sum63(float x) {
    x = dpp_add<0x111>(x); x = dpp_add<0x112>(x); x = dpp_add<0x114>(x);
    x = dpp_add<0x118>(x); x = dpp_add<0x142>(x); x = dpp_add<0x143>(x);
    return x;
}
__device__ __forceinline__ float wave_max63(float x) {
    x = dpp_max<0x111>(x); x = dpp_max<0x112>(x); x = dpp_max<0x114>(x);
    x = dpp_max<0x118>(x); x = dpp_max<0x142>(x); x = dpp_max<0x143>(x);
    return x;
}
__device__ __forceinline__ float rdlane_f(float v, int l) {
    return __int_as_float(__builtin_amdgcn_readlane(__float_as_int(v), l));
}
// RNE float->bf16 bits
__device__ __forceinline__ unsigned bf16_1(float f) {
    unsigned x = __float_as_uint(f);
    return (x + 0x7fffu + ((x >> 16) & 1u)) >> 16;
}
__device__ __forceinline__ unsigned bfpack(float a, float b) {
    return bf16_1(a) | (bf16_1(b) << 16);
}

// ---- k_bin: histogram + self-reserve (slotted buckets) + scatter ----
__global__ __launch_bounds__(256) void k_bin(const int* __restrict__ src,
                                             const int* __restrict__ dst,
                                             unsigned* __restrict__ bcnt,
                                             unsigned* __restrict__ binned) {
    __shared__ unsigned lh[NBKT];
    int t = threadIdx.x;
    unsigned b0 = blockIdx.x * CHUNKB;
    unsigned b1 = min(b0 + CHUNKB, (unsigned)NE);
    if (b0 >= b1) return;
    unsigned n4 = (b1 - b0) >> 2;
    for (int k = t; k < NBKT; k += 256) lh[k] = 0u;
    __syncthreads();
    const int4* d4 = (const int4*)(dst + b0);
    const int4* s4 = (const int4*)(src + b0);
    for (unsigned i = t; i < n4; i += 256) {
        int4 v = d4[i];
        atomicAdd(&lh[((unsigned)v.x) >> 8], 1u);
        atomicAdd(&lh[((unsigned)v.y) >> 8], 1u);
        atomicAdd(&lh[((unsigned)v.z) >> 8], 1u);
        atomicAdd(&lh[((unsigned)v.w) >> 8], 1u);
    }
    __syncthreads();
    for (int k = t; k < NBKT; k += 256) {
        unsigned c = lh[k];
        if (c) lh[k] = (unsigned)k * BSLOT + atomicAdd(&bcnt[k], c);
    }
    __syncthreads();
    for (unsigned i = t; i < n4; i += 256) {
        int4 dv = d4[i];
        int4 sv = s4[i];
        { unsigned d_=(unsigned)dv.x, s_=(unsigned)sv.x;
          unsigned pos=atomicAdd(&lh[d_>>8],1u); binned[pos]=(s_<<8)|(d_&255u); }
        { unsigned d_=(unsigned)dv.y, s_=(unsigned)sv.y;
          unsigned pos=atomicAdd(&lh[d_>>8],1u); binned[pos]=(s_<<8)|(d_&255u); }
        { unsigned d_=(unsigned)dv.z, s_=(unsigned)sv.z;
          unsigned pos=atomicAdd(&lh[d_>>8],1u); binned[pos]=(s_<<8)|(d_&255u); }
        { unsigned d_=(unsigned)dv.w, s_=(unsigned)sv.w;
          unsigned pos=atomicAdd(&lh[d_>>8],1u); binned[pos]=(s_<<8)|(d_&255u); }
    }
}

// =====================================================================
// k_sg: blocks 0..NBKT-1 counting-sort their bucket (perm + rowBE);
// blocks NBKT.. run MFMA GEMM tiles. Zero inter-population data sharing.
// =====================================================================
__global__ __launch_bounds__(256) void k_sg(
    const unsigned* __restrict__ bcnt, const unsigned* __restrict__ binned,
    int* __restrict__ perm, uint2* __restrict__ rowBE,
    const float* __restrict__ feat, const float* __restrict__ W,
    const float* __restrict__ attn_l, const float* __restrict__ attn_r,
    __half* __restrict__ ft, float* __restrict__ el, float* __restrict__ er)
{
    __shared__ __align__(16) char smem[22784];
    int t = threadIdx.x;

    if (blockIdx.x < NBKT) {
        // ---------------- bsort bucket b ----------------
        unsigned* lh    = (unsigned*)smem;            // 256
        unsigned* cur   = (unsigned*)smem + 256;      // 256
        unsigned* stage = (unsigned*)smem + 512;      // BSLOT
        int b = blockIdx.x;
        unsigned beg = (unsigned)b * BSLOT;
        unsigned cnt = min(bcnt[b], (unsigned)BSLOT);
        lh[t] = 0u;
        __syncthreads();
        for (unsigned i = t; i < cnt; i += 256) {
            unsigned w = binned[beg + i];
            stage[i] = w;
            atomicAdd(&lh[w & 255u], 1u);
        }
        __syncthreads();
        for (int off = 1; off < 256; off <<= 1) {     // inclusive scan
            unsigned u = (t >= off) ? lh[t - off] : 0u;
            __syncthreads();
            lh[t] += u;
            __syncthreads();
        }
        unsigned start = (t == 0) ? 0u : lh[t - 1];
        unsigned node = ((unsigned)b << 8) + (unsigned)t;
        if (node < NN) {
            uint2 be; be.x = beg + start; be.y = beg + lh[t];
            rowBE[node] = be;
        }
        cur[t] = start;
        __syncthreads();
        for (unsigned i = t; i < cnt; i += 256) {
            unsigned w = stage[i];
            unsigned pos = atomicAdd(&cur[w & 255u], 1u);
            perm[beg + pos] = (int)(w >> 8);
        }
        return;
    }

    // ---------------- MFMA GEMM tile (proven structure) ----------------
    unsigned short* Ab = (unsigned short*)smem;            // 8192 B
    unsigned short* Bb = (unsigned short*)(smem + 8192);   // 8192 B
    float* wlS = (float*)(smem + 16384);                   // 256 B
    float* wrS = (float*)(smem + 16640);                   // 256 B
    int n0 = (int)(blockIdx.x - NBKT) * 64;

    {
        int k = t >> 2, s = t & 3;
        float pl = 0.f, pr = 0.f;
        #pragma unroll
        for (int q = 0; q < 4; ++q) {
            int seg = s + q * 4;
            float4 f = *(const float4*)(W + k * 64 + seg * 4);
            float4 a = *(const float4*)(attn_l + seg * 4);
            float4 b = *(const float4*)(attn_r + seg * 4);
            pl += f.x*a.x + f.y*a.y + f.z*a.z + f.w*a.w;
            pr += f.x*b.x + f.y*b.y + f.z*b.z + f.w*b.w;
        }
        pl += __shfl_xor(pl, 1, 64); pl += __shfl_xor(pl, 2, 64);
        pr += __shfl_xor(pr, 1, 64); pr += __shfl_xor(pr, 2, 64);
        if (s == 0) { wlS[k] = pl; wrS[k] = pr; }
    }
    {
        int j = t & 63, g = t >> 6;
        unsigned m = (unsigned)((j & 7) << 4);
        #pragma unroll
        for (int i = 0; i < 8; ++i) {
            int k0 = g * 16 + i * 2;
            float w0 = W[k0 * 64 + j];
            float w1 = W[(k0 + 1) * 64 + j];
            *(unsigned*)((char*)Bb + j * 128 + (((unsigned)(k0 * 2)) ^ m)) = bfpack(w0, w1);
        }
    }
    __syncthreads();
    {
        int r = t >> 2, s = t & 3;
        int n = n0 + r;
        bool valid = n < NN;
        const float* fp = feat + (size_t)(valid ? n : (NN - 1)) * D;
        float pl = 0.f, pr = 0.f;
        unsigned m = (unsigned)((r & 7) << 4);
        #pragma unroll
        for (int q = 0; q < 4; ++q) {
            int seg = s + q * 4;
            float4 f = *(const float4*)(fp + seg * 4);
            float4 a = *(const float4*)(wlS + seg * 4);
            float4 b = *(const float4*)(wrS + seg * 4);
            pl += f.x*a.x + f.y*a.y + f.z*a.z + f.w*a.w;
            pr += f.x*b.x + f.y*b.y + f.z*b.z + f.w*b.w;
            uint2 pk;
            pk.x = bfpack(f.x, f.y);
            pk.y = bfpack(f.z, f.w);
            *(uint2*)((char*)Ab + r * 128 + (((unsigned)(seg * 8)) ^ m)) = pk;
        }
        pl += __shfl_xor(pl, 1, 64); pl += __shfl_xor(pl, 2, 64);
        pr += __shfl_xor(pr, 1, 64); pr += __shfl_xor(pr, 2, 64);
        if (s == 0 && valid) { el[n] = pl; er[n] = pr; }
    }
    __syncthreads();

    int w = t >> 6, l = t & 63;
    int lr = l & 15, lg = l >> 4;
    f32x4 acc0 = {0.f,0.f,0.f,0.f};
    f32x4 acc1 = {0.f,0.f,0.f,0.f};
    f32x4 acc2 = {0.f,0.f,0.f,0.f};
    f32x4 acc3 = {0.f,0.f,0.f,0.f};

    int jrow = w * 16 + lr;
    unsigned bm = (unsigned)((jrow & 7) << 4);
    short8 bf0 = *(const short8*)((char*)Bb + jrow * 128 + (((unsigned)(0 + lg * 16)) ^ bm));
    short8 bf1 = *(const short8*)((char*)Bb + jrow * 128 + (((unsigned)(64 + lg * 16)) ^ bm));

    #pragma unroll
    for (int rt = 0; rt < 4; ++rt) {
        int arow = rt * 16 + lr;
        unsigned am = (unsigned)((arow & 7) << 4);
        short8 a0 = *(const short8*)((char*)Ab + arow * 128 + (((unsigned)(0 + lg * 16)) ^ am));
        short8 a1 = *(const short8*)((char*)Ab + arow * 128 + (((unsigned)(64 + lg * 16)) ^ am));
        f32x4 acc = (rt == 0) ? acc0 : (rt == 1) ? acc1 : (rt == 2) ? acc2 : acc3;
        acc = __builtin_amdgcn_mfma_f32_16x16x32_bf16(a0, bf0, acc, 0, 0, 0);
        acc = __builtin_amdgcn_mfma_f32_16x16x32_bf16(a1, bf1, acc, 0, 0, 0);
        if (rt == 0) acc0 = acc; else if (rt == 1) acc1 = acc;
        else if (rt == 2) acc2 = acc; else acc3 = acc;
    }

    int col = w * 16 + lr;
    #pragma unroll
    for (int rt = 0; rt < 4; ++rt) {
        f32x4 acc = (rt == 0) ? acc0 : (rt == 1) ? acc1 : (rt == 2) ? acc2 : acc3;
        #pragma unroll
        for (int i = 0; i < 4; ++i) {
            int row = rt * 16 + lg * 4 + i;
            int nn = n0 + row;
            if (nn < NN) ft[(size_t)nn * D + col] = __float2half(acc[i]);
        }
    }
}

// ---- fallback: full-wave processing of one node (deg > 64) ----
__device__ __noinline__ void agg_node64(int d, int lane, unsigned beg, unsigned end,
                                        const int* __restrict__ perm_src,
                                        const float* __restrict__ el, float er_d,
                                        const __half* __restrict__ ft,
                                        const float* __restrict__ feat,
                                        const float* __restrict__ bias,
                                        float* __restrict__ out) {
    float acc = 0.0f;
    float s = 0.0f;
    float m = -INFINITY;
    for (unsigned base = beg; base < end; base += 64) {
        unsigned i = base + lane;
        float e = -INFINITY;
        if (i < end) {
            int sid2 = perm_src[i];
            float v = el[sid2] + er_d;
            e = v > 0.0f ? v : NEG_SLOPE * v;
        }
        m = fmaxf(m, rdlane_f(wave_max63(e), 63));
    }
    for (unsigned base = beg; base < end; base += 64) {
        unsigned i = base + lane;
        float exx = 0.0f;
        if (i < end) {
            int sid2 = perm_src[i];
            float v = el[sid2] + er_d;
            v = v > 0.0f ? v : NEG_SLOPE * v;
            exx = __expf(v - m);
        }
        s += rdlane_f(wave_sum63(exx), 63);
    }
    for (unsigned jj = beg; jj < end; ++jj) {
        int sj = perm_src[jj];
        float v = el[sj] + er_d;
        v = v > 0.0f ? v : NEG_SLOPE * v;
        acc = fmaf(__half2float(ft[((size_t)sj << 6) + lane]), __expf(v - m), acc);
    }
    acc /= s;
    out[(size_t)d * D + lane] = acc + feat[(size_t)d * D + lane] + bias[lane];
}

// 32-bit byte-offset gather (R10/R15-proven form): base + (sid<<7 | lane<<1)
#define LOAD8(B, J) do { \
    unsigned _o0 = (((unsigned)__builtin_amdgcn_readlane(sid, (J) + 0)) << 7) | lb; \
    unsigned _o1 = (((unsigned)__builtin_amdgcn_readlane(sid, (J) + 1)) << 7) | lb; \
    unsigned _o2 = (((unsigned)__builtin_amdgcn_readlane(sid, (J) + 2)) << 7) | lb; \
    unsigned _o3 = (((unsigned)__builtin_amdgcn_readlane(sid, (J) + 3)) << 7) | lb; \
    unsigned _o4 = (((unsigned)__builtin_amdgcn_readlane(sid, (J) + 4)) << 7) | lb; \
    unsigned _o5 = (((unsigned)__builtin_amdgcn_readlane(sid, (J) + 5)) << 7) | lb; \
    unsigned _o6 = (((unsigned)__builtin_amdgcn_readlane(sid, (J) + 6)) << 7) | lb; \
    unsigned _o7 = (((unsigned)__builtin_amdgcn_readlane(sid, (J) + 7)) << 7) | lb; \
    B##0 = *(const __half*)(ftb + _o0); \
    B##1 = *(const __half*)(ftb + _o1); \
    B##2 = *(const __half*)(ftb + _o2); \
    B##3 = *(const __half*)(ftb + _o3); \
    B##4 = *(const __half*)(ftb + _o4); \
    B##5 = *(const __half*)(ftb + _o5); \
    B##6 = *(const __half*)(ftb + _o6); \
    B##7 = *(const __half*)(ftb + _o7); \
} while (0)

#define FMA8(B, J) do { \
    acc = fmaf(__half2float(B##0), rdlane_f(ex, (J) + 0), acc); \
    acc = fmaf(__half2float(B##1), rdlane_f(ex, (J) + 1), acc); \
    acc = fmaf(__half2float(B##2), rdlane_f(ex, (J) + 2), acc); \
    acc = fmaf(__half2float(B##3), rdlane_f(ex, (J) + 3), acc); \
    acc = fmaf(__half2float(B##4), rdlane_f(ex, (J) + 4), acc); \
    acc = fmaf(__half2float(B##5), rdlane_f(ex, (J) + 5), acc); \
    acc = fmaf(__half2float(B##6), rdlane_f(ex, (J) + 6), acc); \
    acc = fmaf(__half2float(B##7), rdlane_f(ex, (J) + 7), acc); \
} while (0)

// fused edge-softmax + aggregation, one wave per node, software-pipelined.
__global__ __launch_bounds__(256) void k_agg(const uint2* __restrict__ rowBE,
                                             const int* __restrict__ perm_src,
                                             const float* __restrict__ el,
                                             const float* __restrict__ er,
                                             const __half* __restrict__ ft,
                                             const float* __restrict__ feat,
                                             const float* __restrict__ bias,
                                             float* __restrict__ out) {
    int gid = blockIdx.x * 256 + threadIdx.x;
    int d = gid >> 6;
    int lane = gid & 63;
    if (d >= NN) return;

    uint2 be = rowBE[d];
    unsigned beg = be.x;
    int deg = (int)(be.y - be.x);
    float er_d = er[d];

    if (deg > 64) {
        agg_node64(d, lane, be.x, be.y, perm_src, el, er_d, ft, feat, bias, out);
        return;
    }
    if (deg == 0) {
        out[(size_t)d * D + lane] = feat[(size_t)d * D + lane] + bias[lane];
        return;
    }

    int sid = perm_src[beg + ((lane < deg) ? lane : 0)];
    float elv = el[sid];                      // issued early
    float fv = feat[(size_t)d * D + lane];    // independent; issued early
    float bv = bias[lane];

    const char* ftb = (const char*)ft;
    unsigned lb = (unsigned)lane << 1;

    __half c0, c1, c2, c3, c4, c5, c6, c7;
    __half n0, n1, n2, n3, n4, n5, n6, n7;
    LOAD8(c, 0);                              // batch 0 in flight during softmax

    float e = elv + er_d;
    e = e > 0.0f ? e : NEG_SLOPE * e;
    float ex = (lane < deg) ? __expf(e) : 0.0f;   // no max-subtract (bounded e)
    float s = rdlane_f(wave_sum63(ex), 63);
    float inv_s = __frcp_rn(s);

    float acc = 0.0f;
    int j = 0;
    while (true) {
        bool more = (j + 8) < deg;
        if (more) LOAD8(n, j + 8);
        FMA8(c, j);
        j += 8;
        if (!more) break;
        bool more2 = (j + 8) < deg;
        if (more2) LOAD8(c, j + 8);
        FMA8(n, j);
        j += 8;
        if (!more2) break;
    }
    acc *= inv_s;
    out[(size_t)d * D + lane] = acc + fv + bv;
}

extern "C" void kernel_launch(void* const* d_in, const int* in_sizes, int n_in,
                              void* d_out, int out_size, void* d_ws, size_t ws_size,
                              hipStream_t stream) {
    const float* feat   = (const float*)d_in[0];
    const float* W      = (const float*)d_in[1];
    const float* attn_l = (const float*)d_in[2];
    const float* attn_r = (const float*)d_in[3];
    const float* bias   = (const float*)d_in[4];
    const int*   src    = (const int*)d_in[5];
    const int*   dst    = (const int*)d_in[6];
    float* out = (float*)d_out;

    char* ws = (char*)d_ws;
    __half*   ft     = (__half*)(ws);                // 12,800,000
    float*    el     = (float*)(ws + 12800000);      // 400,000
    float*    er     = (float*)(ws + 13200000);      // 400,000
    int*      perm   = (int*)(ws + 13600000);        // 8,007,680 -> 21,607,680
    uint2*    rowBE  = (uint2*)(ws + 21607680);      // 800,000 -> 22,407,680
    unsigned* bcnt   = (unsigned*)(ws + 22407680);   // 1,564 -> 22,409,244
    unsigned* binned = (unsigned*)(ws + 22409248);   // 8,007,680 -> 30,416,928

    hipMemsetAsync(bcnt, 0, NBKT * sizeof(unsigned), stream);
    k_bin<<<NBIN, 256, 0, stream>>>(src, dst, bcnt, binned);
    k_sg<<<NBKT + NTILE, 256, 0, stream>>>(bcnt, binned, perm, rowBE,
                                           feat, W, attn_l, attn_r, ft, el, er);
    k_agg<<<(NN * 64 + 255) / 256, 256, 0, stream>>>(rowBE, perm, el, er,
                                                     ft, feat, bias, out);
}

// Round 22
// 92.603 us; speedup vs baseline: 1.1241x; 1.1241x over previous
//
#include <hip/hip_runtime.h>
#include <hip/hip_fp16.h>
#include <math.h>

#define NN 100000
#define NE 1600000
#define D 64
#define NEG_SLOPE 0.2f
#define NBKT 391          // ceil(NN/256) buckets of 256 dst nodes
#define NBIN 391          // bin blocks
#define CHUNKB 4096       // edges per bin block (391*4096 >= NE, %4==0)
#define BSLOT 5120        // slots per bucket (mean 4096, sd 64)
#define NTILE 1563        // ceil(NN/64) GEMM tiles

typedef __attribute__((ext_vector_type(8))) short short8;
typedef __attribute__((ext_vector_type(4))) float f32x4;

// ---------------- DPP wave reductions (VALU pipe, no LDS) ----------------
template<int CTRL>
__device__ __forceinline__ float dpp_add(float x) {
    int y = __builtin_amdgcn_update_dpp(0, __float_as_int(x), CTRL, 0xf, 0xf, true);
    return x + __int_as_float(y);
}
template<int CTRL>
__device__ __forceinline__ float dpp_max(float x) {
    int xi = __float_as_int(x);
    int y = __builtin_amdgcn_update_dpp(xi, xi, CTRL, 0xf, 0xf, false);
    return fmaxf(x, __int_as_float(y));
}
__device__ __forceinline__ float wave_sum63(float x) {
    x = dpp_add<0x111>(x); x = dpp_add<0x112>(x); x = dpp_add<0x114>(x);
    x = dpp_add<0x118>(x); x = dpp_add<0x142>(x); x = dpp_add<0x143>(x);
    return x;
}
__device__ __forceinline__ float wave_max63(float x) {
    x = dpp_max<0x111>(x); x = dpp_max<0x112>(x); x = dpp_max<0x114>(x);
    x = dpp_max<0x118>(x); x = dpp_max<0x142>(x); x = dpp_max<0x143>(x);
    return x;
}
__device__ __forceinline__ float rdlane_f(float v, int l) {
    return __int_as_float(__builtin_amdgcn_readlane(__float_as_int(v), l));
}
// RNE float->bf16 bits
__device__ __forceinline__ unsigned bf16_1(float f) {
    unsigned x = __float_as_uint(f);
    return (x + 0x7fffu + ((x >> 16) & 1u)) >> 16;
}
__device__ __forceinline__ unsigned bfpack(float a, float b) {
    return bf16_1(a) | (bf16_1(b) << 16);
}

// ---- k_bin: histogram + self-reserve (slotted buckets) + scatter ----
__global__ __launch_bounds__(256) void k_bin(const int* __restrict__ src,
                                             const int* __restrict__ dst,
                                             unsigned* __restrict__ bcnt,
                                             unsigned* __restrict__ binned) {
    __shared__ unsigned lh[NBKT];
    int t = threadIdx.x;
    unsigned b0 = blockIdx.x * CHUNKB;
    unsigned b1 = min(b0 + CHUNKB, (unsigned)NE);
    if (b0 >= b1) return;
    unsigned n4 = (b1 - b0) >> 2;
    for (int k = t; k < NBKT; k += 256) lh[k] = 0u;
    __syncthreads();
    const int4* d4 = (const int4*)(dst + b0);
    const int4* s4 = (const int4*)(src + b0);
    for (unsigned i = t; i < n4; i += 256) {
        int4 v = d4[i];
        atomicAdd(&lh[((unsigned)v.x) >> 8], 1u);
        atomicAdd(&lh[((unsigned)v.y) >> 8], 1u);
        atomicAdd(&lh[((unsigned)v.z) >> 8], 1u);
        atomicAdd(&lh[((unsigned)v.w) >> 8], 1u);
    }
    __syncthreads();
    for (int k = t; k < NBKT; k += 256) {
        unsigned c = lh[k];
        if (c) lh[k] = (unsigned)k * BSLOT + atomicAdd(&bcnt[k], c);
    }
    __syncthreads();
    for (unsigned i = t; i < n4; i += 256) {
        int4 dv = d4[i];
        int4 sv = s4[i];
        { unsigned d_=(unsigned)dv.x, s_=(unsigned)sv.x;
          unsigned pos=atomicAdd(&lh[d_>>8],1u); binned[pos]=(s_<<8)|(d_&255u); }
        { unsigned d_=(unsigned)dv.y, s_=(unsigned)sv.y;
          unsigned pos=atomicAdd(&lh[d_>>8],1u); binned[pos]=(s_<<8)|(d_&255u); }
        { unsigned d_=(unsigned)dv.z, s_=(unsigned)sv.z;
          unsigned pos=atomicAdd(&lh[d_>>8],1u); binned[pos]=(s_<<8)|(d_&255u); }
        { unsigned d_=(unsigned)dv.w, s_=(unsigned)sv.w;
          unsigned pos=atomicAdd(&lh[d_>>8],1u); binned[pos]=(s_<<8)|(d_&255u); }
    }
}

// =====================================================================
// k_sg: blocks 0..NBKT-1 counting-sort their bucket (perm + rowBE);
// blocks NBKT.. run MFMA GEMM tiles. Zero inter-population data sharing.
// =====================================================================
__global__ __launch_bounds__(256) void k_sg(
    const unsigned* __restrict__ bcnt, const unsigned* __restrict__ binned,
    int* __restrict__ perm, uint2* __restrict__ rowBE,
    const float* __restrict__ feat, const float* __restrict__ W,
    const float* __restrict__ attn_l, const float* __restrict__ attn_r,
    __half* __restrict__ ft, float* __restrict__ el, float* __restrict__ er)
{
    __shared__ __align__(16) char smem[22784];
    int t = threadIdx.x;

    if (blockIdx.x < NBKT) {
        // ---------------- bsort bucket b ----------------
        unsigned* lh    = (unsigned*)smem;            // 256
        unsigned* cur   = (unsigned*)smem + 256;      // 256
        unsigned* stage = (unsigned*)smem + 512;      // BSLOT
        int b = blockIdx.x;
        unsigned beg = (unsigned)b * BSLOT;
        unsigned cnt = min(bcnt[b], (unsigned)BSLOT);
        lh[t] = 0u;
        __syncthreads();
        for (unsigned i = t; i < cnt; i += 256) {
            unsigned w = binned[beg + i];
            stage[i] = w;
            atomicAdd(&lh[w & 255u], 1u);
        }
        __syncthreads();
        for (int off = 1; off < 256; off <<= 1) {     // inclusive scan
            unsigned u = (t >= off) ? lh[t - off] : 0u;
            __syncthreads();
            lh[t] += u;
            __syncthreads();
        }
        unsigned start = (t == 0) ? 0u : lh[t - 1];
        unsigned node = ((unsigned)b << 8) + (unsigned)t;
        if (node < NN) {
            uint2 be; be.x = beg + start; be.y = beg + lh[t];
            rowBE[node] = be;
        }
        cur[t] = start;
        __syncthreads();
        for (unsigned i = t; i < cnt; i += 256) {
            unsigned w = stage[i];
            unsigned pos = atomicAdd(&cur[w & 255u], 1u);
            perm[beg + pos] = (int)(w >> 8);
        }
        return;
    }

    // ---------------- MFMA GEMM tile (proven structure) ----------------
    unsigned short* Ab = (unsigned short*)smem;            // 8192 B
    unsigned short* Bb = (unsigned short*)(smem + 8192);   // 8192 B
    float* wlS = (float*)(smem + 16384);                   // 256 B
    float* wrS = (float*)(smem + 16640);                   // 256 B
    int n0 = (int)(blockIdx.x - NBKT) * 64;

    {
        int k = t >> 2, s = t & 3;
        float pl = 0.f, pr = 0.f;
        #pragma unroll
        for (int q = 0; q < 4; ++q) {
            int seg = s + q * 4;
            float4 f = *(const float4*)(W + k * 64 + seg * 4);
            float4 a = *(const float4*)(attn_l + seg * 4);
            float4 b = *(const float4*)(attn_r + seg * 4);
            pl += f.x*a.x + f.y*a.y + f.z*a.z + f.w*a.w;
            pr += f.x*b.x + f.y*b.y + f.z*b.z + f.w*b.w;
        }
        pl += __shfl_xor(pl, 1, 64); pl += __shfl_xor(pl, 2, 64);
        pr += __shfl_xor(pr, 1, 64); pr += __shfl_xor(pr, 2, 64);
        if (s == 0) { wlS[k] = pl; wrS[k] = pr; }
    }
    {
        int j = t & 63, g = t >> 6;
        unsigned m = (unsigned)((j & 7) << 4);
        #pragma unroll
        for (int i = 0; i < 8; ++i) {
            int k0 = g * 16 + i * 2;
            float w0 = W[k0 * 64 + j];
            float w1 = W[(k0 + 1) * 64 + j];
            *(unsigned*)((char*)Bb + j * 128 + (((unsigned)(k0 * 2)) ^ m)) = bfpack(w0, w1);
        }
    }
    __syncthreads();
    {
        int r = t >> 2, s = t & 3;
        int n = n0 + r;
        bool valid = n < NN;
        const float* fp = feat + (size_t)(valid ? n : (NN - 1)) * D;
        float pl = 0.f, pr = 0.f;
        unsigned m = (unsigned)((r & 7) << 4);
        #pragma unroll
        for (int q = 0; q < 4; ++q) {
            int seg = s + q * 4;
            float4 f = *(const float4*)(fp + seg * 4);
            float4 a = *(const float4*)(wlS + seg * 4);
            float4 b = *(const float4*)(wrS + seg * 4);
            pl += f.x*a.x + f.y*a.y + f.z*a.z + f.w*a.w;
            pr += f.x*b.x + f.y*b.y + f.z*b.z + f.w*b.w;
            uint2 pk;
            pk.x = bfpack(f.x, f.y);
            pk.y = bfpack(f.z, f.w);
            *(uint2*)((char*)Ab + r * 128 + (((unsigned)(seg * 8)) ^ m)) = pk;
        }
        pl += __shfl_xor(pl, 1, 64); pl += __shfl_xor(pl, 2, 64);
        pr += __shfl_xor(pr, 1, 64); pr += __shfl_xor(pr, 2, 64);
        if (s == 0 && valid) { el[n] = pl; er[n] = pr; }
    }
    __syncthreads();

    int w = t >> 6, l = t & 63;
    int lr = l & 15, lg = l >> 4;
    f32x4 acc0 = {0.f,0.f,0.f,0.f};
    f32x4 acc1 = {0.f,0.f,0.f,0.f};
    f32x4 acc2 = {0.f,0.f,0.f,0.f};
    f32x4 acc3 = {0.f,0.f,0.f,0.f};

    int jrow = w * 16 + lr;
    unsigned bm = (unsigned)((jrow & 7) << 4);
    short8 bf0 = *(const short8*)((char*)Bb + jrow * 128 + (((unsigned)(0 + lg * 16)) ^ bm));
    short8 bf1 = *(const short8*)((char*)Bb + jrow * 128 + (((unsigned)(64 + lg * 16)) ^ bm));

    #pragma unroll
    for (int rt = 0; rt < 4; ++rt) {
        int arow = rt * 16 + lr;
        unsigned am = (unsigned)((arow & 7) << 4);
        short8 a0 = *(const short8*)((char*)Ab + arow * 128 + (((unsigned)(0 + lg * 16)) ^ am));
        short8 a1 = *(const short8*)((char*)Ab + arow * 128 + (((unsigned)(64 + lg * 16)) ^ am));
        f32x4 acc = (rt == 0) ? acc0 : (rt == 1) ? acc1 : (rt == 2) ? acc2 : acc3;
        acc = __builtin_amdgcn_mfma_f32_16x16x32_bf16(a0, bf0, acc, 0, 0, 0);
        acc = __builtin_amdgcn_mfma_f32_16x16x32_bf16(a1, bf1, acc, 0, 0, 0);
        if (rt == 0) acc0 = acc; else if (rt == 1) acc1 = acc;
        else if (rt == 2) acc2 = acc; else acc3 = acc;
    }

    int col = w * 16 + lr;
    #pragma unroll
    for (int rt = 0; rt < 4; ++rt) {
        f32x4 acc = (rt == 0) ? acc0 : (rt == 1) ? acc1 : (rt == 2) ? acc2 : acc3;
        #pragma unroll
        for (int i = 0; i < 4; ++i) {
            int row = rt * 16 + lg * 4 + i;
            int nn = n0 + row;
            if (nn < NN) ft[(size_t)nn * D + col] = __float2half(acc[i]);
        }
    }
}

// ---- fallback: full-wave processing of one node (deg > 64) ----
__device__ __noinline__ void agg_node64(int d, int lane, unsigned beg, unsigned end,
                                        const int* __restrict__ perm_src,
                                        const float* __restrict__ el, float er_d,
                                        const __half* __restrict__ ft,
                                        const float* __restrict__ feat,
                                        const float* __restrict__ bias,
                                        float* __restrict__ out) {
    float acc = 0.0f;
    float s = 0.0f;
    float m = -INFINITY;
    for (unsigned base = beg; base < end; base += 64) {
        unsigned i = base + lane;
        float e = -INFINITY;
        if (i < end) {
            int sid2 = perm_src[i];
            float v = el[sid2] + er_d;
            e = v > 0.0f ? v : NEG_SLOPE * v;
        }
        m = fmaxf(m, rdlane_f(wave_max63(e), 63));
    }
    for (unsigned base = beg; base < end; base += 64) {
        unsigned i = base + lane;
        float exx = 0.0f;
        if (i < end) {
            int sid2 = perm_src[i];
            float v = el[sid2] + er_d;
            v = v > 0.0f ? v : NEG_SLOPE * v;
            exx = __expf(v - m);
        }
        s += rdlane_f(wave_sum63(exx), 63);
    }
    for (unsigned jj = beg; jj < end; ++jj) {
        int sj = perm_src[jj];
        float v = el[sj] + er_d;
        v = v > 0.0f ? v : NEG_SLOPE * v;
        acc = fmaf(__half2float(ft[((size_t)sj << 6) + lane]), __expf(v - m), acc);
    }
    acc /= s;
    out[(size_t)d * D + lane] = acc + feat[(size_t)d * D + lane] + bias[lane];
}

// 32-bit byte-offset gather (R10/R15-proven form): base + (sid<<7 | lane<<1)
#define LOAD8(B, J) do { \
    unsigned _o0 = (((unsigned)__builtin_amdgcn_readlane(sid, (J) + 0)) << 7) | lb; \
    unsigned _o1 = (((unsigned)__builtin_amdgcn_readlane(sid, (J) + 1)) << 7) | lb; \
    unsigned _o2 = (((unsigned)__builtin_amdgcn_readlane(sid, (J) + 2)) << 7) | lb; \
    unsigned _o3 = (((unsigned)__builtin_amdgcn_readlane(sid, (J) + 3)) << 7) | lb; \
    unsigned _o4 = (((unsigned)__builtin_amdgcn_readlane(sid, (J) + 4)) << 7) | lb; \
    unsigned _o5 = (((unsigned)__builtin_amdgcn_readlane(sid, (J) + 5)) << 7) | lb; \
    unsigned _o6 = (((unsigned)__builtin_amdgcn_readlane(sid, (J) + 6)) << 7) | lb; \
    unsigned _o7 = (((unsigned)__builtin_amdgcn_readlane(sid, (J) + 7)) << 7) | lb; \
    B##0 = *(const __half*)(ftb + _o0); \
    B##1 = *(const __half*)(ftb + _o1); \
    B##2 = *(const __half*)(ftb + _o2); \
    B##3 = *(const __half*)(ftb + _o3); \
    B##4 = *(const __half*)(ftb + _o4); \
    B##5 = *(const __half*)(ftb + _o5); \
    B##6 = *(const __half*)(ftb + _o6); \
    B##7 = *(const __half*)(ftb + _o7); \
} while (0)

#define FMA8(B, J) do { \
    acc = fmaf(__half2float(B##0), rdlane_f(ex, (J) + 0), acc); \
    acc = fmaf(__half2float(B##1), rdlane_f(ex, (J) + 1), acc); \
    acc = fmaf(__half2float(B##2), rdlane_f(ex, (J) + 2), acc); \
    acc = fmaf(__half2float(B##3), rdlane_f(ex, (J) + 3), acc); \
    acc = fmaf(__half2float(B##4), rdlane_f(ex, (J) + 4), acc); \
    acc = fmaf(__half2float(B##5), rdlane_f(ex, (J) + 5), acc); \
    acc = fmaf(__half2float(B##6), rdlane_f(ex, (J) + 6), acc); \
    acc = fmaf(__half2float(B##7), rdlane_f(ex, (J) + 7), acc); \
} while (0)

// fused edge-softmax + aggregation, one wave per node, software-pipelined.
__global__ __launch_bounds__(256) void k_agg(const uint2* __restrict__ rowBE,
                                             const int* __restrict__ perm_src,
                                             const float* __restrict__ el,
                                             const float* __restrict__ er,
                                             const __half* __restrict__ ft,
                                             const float* __restrict__ feat,
                                             const float* __restrict__ bias,
                                             float* __restrict__ out) {
    int gid = blockIdx.x * 256 + threadIdx.x;
    int d = gid >> 6;
    int lane = gid & 63;
    if (d >= NN) return;

    uint2 be = rowBE[d];
    unsigned beg = be.x;
    int deg = (int)(be.y - be.x);
    float er_d = er[d];

    if (deg > 64) {
        agg_node64(d, lane, be.x, be.y, perm_src, el, er_d, ft, feat, bias, out);
        return;
    }
    if (deg == 0) {
        out[(size_t)d * D + lane] = feat[(size_t)d * D + lane] + bias[lane];
        return;
    }

    int sid = perm_src[beg + ((lane < deg) ? lane : 0)];
    float elv = el[sid];                      // issued early
    float fv = feat[(size_t)d * D + lane];    // independent; issued early
    float bv = bias[lane];

    const char* ftb = (const char*)ft;
    unsigned lb = (unsigned)lane << 1;

    __half c0, c1, c2, c3, c4, c5, c6, c7;
    __half n0, n1, n2, n3, n4, n5, n6, n7;
    LOAD8(c, 0);                              // batch 0 in flight during softmax

    float e = elv + er_d;
    e = e > 0.0f ? e : NEG_SLOPE * e;
    float ex = (lane < deg) ? __expf(e) : 0.0f;   // no max-subtract (bounded e)
    float s = rdlane_f(wave_sum63(ex), 63);
    float inv_s = __frcp_rn(s);

    float acc = 0.0f;
    int j = 0;
    while (true) {
        bool more = (j + 8) < deg;
        if (more) LOAD8(n, j + 8);
        FMA8(c, j);
        j += 8;
        if (!more) break;
        bool more2 = (j + 8) < deg;
        if (more2) LOAD8(c, j + 8);
        FMA8(n, j);
        j += 8;
        if (!more2) break;
    }
    acc *= inv_s;
    out[(size_t)d * D + lane] = acc + fv + bv;
}

extern "C" void kernel_launch(void* const* d_in, const int* in_sizes, int n_in,
                              void* d_out, int out_size, void* d_ws, size_t ws_size,
                              hipStream_t stream) {
    const float* feat   = (const float*)d_in[0];
    const float* W      = (const float*)d_in[1];
    const float* attn_l = (const float*)d_in[2];
    const float* attn_r = (const float*)d_in[3];
    const float* bias   = (const float*)d_in[4];
    const int*   src    = (const int*)d_in[5];
    const int*   dst    = (const int*)d_in[6];
    float* out = (float*)d_out;

    char* ws = (char*)d_ws;
    __half*   ft     = (__half*)(ws);                // 12,800,000
    float*    el     = (float*)(ws + 12800000);      // 400,000
    float*    er     = (float*)(ws + 13200000);      // 400,000
    int*      perm   = (int*)(ws + 13600000);        // 8,007,680 -> 21,607,680
    uint2*    rowBE  = (uint2*)(ws + 21607680);      // 800,000 -> 22,407,680
    unsigned* bcnt   = (unsigned*)(ws + 22407680);   // 1,564 -> 22,409,244
    unsigned* binned = (unsigned*)(ws + 22409248);   // 8,007,680 -> 30,416,928

    hipMemsetAsync(bcnt, 0, NBKT * sizeof(unsigned), stream);
    k_bin<<<NBIN, 256, 0, stream>>>(src, dst, bcnt, binned);
    k_sg<<<NBKT + NTILE, 256, 0, stream>>>(bcnt, binned, perm, rowBE,
                                           feat, W, attn_l, attn_r, ft, el, er);
    k_agg<<<(NN * 64 + 255) / 256, 256, 0, stream>>>(rowBE, perm, el, er,
                                                     ft, feat, bias, out);
}